// Round 5
// baseline (527.966 us; speedup 1.0000x reference)
//
#include <hip/hip_runtime.h>
#include <stdint.h>

#define T_DIM 512
#define B_DIM 128
#define I_DIM 1024
#define N_DIM 1024
#define NB (N_DIM * B_DIM)     // 131072
#define ROWB 4096              // combined W row bytes: I * (hi+lo f16)

#define DECAY 0.9f
#define THRESH 1.0f

typedef _Float16 f16;
typedef _Float16 f16x8 __attribute__((ext_vector_type(8)));
typedef float f32x4 __attribute__((ext_vector_type(4)));

// -------------------------------------------------------------------------
// Split fp32 W -> combined f16 hi/lo layout: [row][kc=0..127][hl][8 f16].
// -------------------------------------------------------------------------
__global__ __launch_bounds__(256) void split_w_kernel(
    const float* __restrict__ W, f16* __restrict__ Ws)
{
    int gid = blockIdx.x * 256 + threadIdx.x;       // N*I/8 kchunks
    int kc  = gid & 127;
    int row = gid >> 7;
    const float* src = W + (size_t)row * I_DIM + kc * 8;
    f16* dst = Ws + (size_t)row * 2048 + kc * 16;
    float v[8];
    *(float4*)&v[0] = *(const float4*)src;
    *(float4*)&v[4] = *(const float4*)(src + 4);
    f16 hi[8], lo[8];
    #pragma unroll
    for (int j = 0; j < 8; ++j) {
        hi[j] = (f16)v[j];
        lo[j] = (f16)(v[j] - (float)hi[j]);
    }
    *(f16x8*)dst       = *(const f16x8*)hi;
    *(f16x8*)(dst + 8) = *(const f16x8*)lo;
}

// -------------------------------------------------------------------------
// GEMM via fp16-split 3xMFMA. Round-3 geometry: 128n x 128b tile per block
// for one t, 4 waves (wave tile 64x64), BK=32, 2x32KB LDS dbuf, 2 blk/CU.
// A (W): combined f16 hi/lo from LDS. B (X): fp32 in LDS, converted to
// f16 hi/lo in registers per K-tile (overlapped with A ds_reads).
// Pipeline: s_barrier / stage-next / s_waitcnt vmcnt(8) / s_barrier —
// next tile's 8 global_load_lds stay in flight across the MFMA cluster.
// MFMA issued term-outer: 16 independent ops between acc reuses.
// -------------------------------------------------------------------------
__global__ __launch_bounds__(256, 2) void spk_gemm_kernel(
    const uint8_t* __restrict__ Wsb,   // combined W [N][kc][hl][8]
    const float* __restrict__ X,       // [B, T, I] fp32
    float* __restrict__ C,             // [tc, N, B] chunk
    int t0)
{
    __shared__ __align__(16) uint8_t lds[65536];   // 2 x (A 16K | B 16K)

    const int tid  = threadIdx.x;
    const int wave = tid >> 6, lane = tid & 63;

    // bijective chunked XCD swizzle: same-t blocks colocate on one XCD
    const int nwg = gridDim.x;
    const int q = nwg >> 3, r = nwg & 7;
    const int xcd = blockIdx.x & 7, idx = blockIdx.x >> 3;
    const int wg = (xcd < r ? xcd * (q + 1) : r * (q + 1) + (xcd - r) * q) + idx;
    const int n0 = (wg & 7) << 7;
    const int t  = t0 + (wg >> 3);

    // staging: 8 granules (16B) per thread; LDS dest linear (granule G*16),
    // source granule XOR-swizzled within each 128B row-chunk.
    // c<4: A (W combined), G=c*256+tid in [0,1024). c>=4: B (X fp32).
    const uint8_t* srcp[8];
    #pragma unroll
    for (int c = 0; c < 8; ++c) {
        if (c < 4) {
            int G = c * 256 + tid;
            int rr = G >> 3, g = G & 7;
            srcp[c] = Wsb + (size_t)(n0 + rr) * ROWB + ((g ^ (rr & 7)) << 4);
        } else {
            int G = (c - 4) * 256 + tid;
            int rr = G >> 3, g = G & 7;
            srcp[c] = (const uint8_t*)X + ((size_t)rr * T_DIM + t) * (I_DIM * 4)
                      + ((g ^ (rr & 7)) << 4);
        }
    }

    const int wr = ((wave >> 1) << 6);   // n-offset 0/64
    const int wc = ((wave & 1) << 6);    // b-offset 0/64
    const int l15 = lane & 15, kcg = lane >> 4, l7 = l15 & 7;

    // frag LDS byte offsets within a buffer
    int aoffH[4], aoffL[4], boff0[4], boff1[4];
    #pragma unroll
    for (int m = 0; m < 4; ++m) {
        int ra = wr + m * 16 + l15;                 // ra&7 == l7
        aoffH[m] = ra * 128 + ((((kcg << 1) | 0) ^ l7) << 4);
        aoffL[m] = ra * 128 + ((((kcg << 1) | 1) ^ l7) << 4);
        int rb = wc + m * 16 + l15;
        boff0[m] = 16384 + rb * 128 + (((kcg * 2 + 0) ^ l7) << 4);
        boff1[m] = 16384 + rb * 128 + (((kcg * 2 + 1) ^ l7) << 4);
    }

    f32x4 acc[4][4];
    #pragma unroll
    for (int m = 0; m < 4; ++m)
        #pragma unroll
        for (int n = 0; n < 4; ++n) acc[m][n] = (f32x4){0.f, 0.f, 0.f, 0.f};

    // prologue: stage tile 0 into buffer 0
    #pragma unroll
    for (int c = 0; c < 8; ++c)
        __builtin_amdgcn_global_load_lds(
            (const __attribute__((address_space(1))) uint8_t*)srcp[c],
            (__attribute__((address_space(3))) uint8_t*)&lds[(c * 256 + tid - lane) * 16],
            16, 0, 0);

    for (int kt = 0; kt < 32; ++kt) {
        const int buf = kt & 1;
        // barrier 1: all waves done reading buf^1 (tile kt-1) -> safe to overwrite
        __builtin_amdgcn_s_barrier();
        if (kt + 1 < 32) {
            const int nb = (buf ^ 1) << 15;
            #pragma unroll
            for (int c = 0; c < 8; ++c)
                __builtin_amdgcn_global_load_lds(
                    (const __attribute__((address_space(1))) uint8_t*)(srcp[c] + (kt + 1) * 128),
                    (__attribute__((address_space(3))) uint8_t*)&lds[nb + (c * 256 + tid - lane) * 16],
                    16, 0, 0);
            asm volatile("s_waitcnt vmcnt(8)" ::: "memory");   // tile kt resident (mine)
        } else {
            asm volatile("s_waitcnt vmcnt(0)" ::: "memory");
        }
        // barrier 2: every wave certified its tile-kt loads
        __builtin_amdgcn_s_barrier();
        __builtin_amdgcn_sched_barrier(0);

        const uint8_t* bp = &lds[buf << 15];

        // B fp32 reads + A combined reads; convert B while A is in flight
        f32x4 b0[4], b1[4];
        #pragma unroll
        for (int n = 0; n < 4; ++n) {
            b0[n] = *(const f32x4*)&bp[boff0[n]];
            b1[n] = *(const f32x4*)&bp[boff1[n]];
        }
        f16x8 Ah[4], Al[4];
        #pragma unroll
        for (int m = 0; m < 4; ++m) {
            Ah[m] = *(const f16x8*)&bp[aoffH[m]];
            Al[m] = *(const f16x8*)&bp[aoffL[m]];
        }
        f16x8 Bh[4], Bl[4];
        #pragma unroll
        for (int n = 0; n < 4; ++n) {
            float bf[8];
            bf[0] = b0[n][0]; bf[1] = b0[n][1]; bf[2] = b0[n][2]; bf[3] = b0[n][3];
            bf[4] = b1[n][0]; bf[5] = b1[n][1]; bf[6] = b1[n][2]; bf[7] = b1[n][3];
            #pragma unroll
            for (int j = 0; j < 8; ++j) {
                f16 h = (f16)bf[j];
                Bh[n][j] = h;
                Bl[n][j] = (f16)(bf[j] - (float)h);
            }
        }

        // 48 MFMAs, term-outer: 16 independent ops between acc reuses
        __builtin_amdgcn_s_setprio(1);
        #pragma unroll
        for (int m = 0; m < 4; ++m)
            #pragma unroll
            for (int n = 0; n < 4; ++n)
                acc[m][n] = __builtin_amdgcn_mfma_f32_16x16x32_f16(Ah[m], Bh[n], acc[m][n], 0, 0, 0);
        #pragma unroll
        for (int m = 0; m < 4; ++m)
            #pragma unroll
            for (int n = 0; n < 4; ++n)
                acc[m][n] = __builtin_amdgcn_mfma_f32_16x16x32_f16(Ah[m], Bl[n], acc[m][n], 0, 0, 0);
        #pragma unroll
        for (int m = 0; m < 4; ++m)
            #pragma unroll
            for (int n = 0; n < 4; ++n)
                acc[m][n] = __builtin_amdgcn_mfma_f32_16x16x32_f16(Al[m], Bh[n], acc[m][n], 0, 0, 0);
        __builtin_amdgcn_s_setprio(0);
    }

    // epilogue: C[t'][n][b]; C/D map col=lane&15, row=(lane>>4)*4+j
    float* cp = C + (size_t)(wg >> 3) * NB;
    const int rg = (lane >> 4) << 2;
    #pragma unroll
    for (int m = 0; m < 4; ++m) {
        int nrow = n0 + wr + m * 16 + rg;
        #pragma unroll
        for (int n = 0; n < 4; ++n) {
            int col = wc + n * 16 + l15;
            #pragma unroll
            for (int j = 0; j < 4; ++j)
                cp[(size_t)(nrow + j) * B_DIM + col] = acc[m][n][j];
        }
    }
}

// -------------------------------------------------------------------------
// Sequential LIF scan per (n,b); state carried across chunk launches.
// -------------------------------------------------------------------------
__global__ __launch_bounds__(256) void spk_scan_kernel(
    const float* __restrict__ cur,   // [tc, NB]
    float* __restrict__ mp_state,    // [NB]
    float* __restrict__ out,         // [NB]
    int tc, int first)
{
    const int nb = blockIdx.x * 256 + threadIdx.x;
    float mp, cnt;
    if (first) { mp = 0.0f; cnt = 0.0f; }
    else       { mp = mp_state[nb]; cnt = out[nb]; }

    const float* p = cur + nb;
    #pragma unroll 8
    for (int t = 0; t < tc; ++t) {
        float c = p[(size_t)t * NB];
        mp = __fadd_rn(__fmul_rn(DECAY, mp), c);
        if (mp >= THRESH) { cnt += 1.0f; mp = 0.0f; }
    }
    mp_state[nb] = mp;
    out[nb] = cnt;
}

extern "C" void kernel_launch(void* const* d_in, const int* in_sizes, int n_in,
                              void* d_out, int out_size, void* d_ws, size_t ws_size,
                              hipStream_t stream) {
    const float* x = (const float*)d_in[0];   // [B, T, I]
    const float* w = (const float*)d_in[1];   // [N, I]
    float* out = (float*)d_out;               // [N, B]

    uint8_t* ws = (uint8_t*)d_ws;
    float* mp  = (float*)ws;                                 // 512 KB
    f16*   Wsp = (f16*)(ws + 524288);                        // 4 MB combined W
    uint8_t* rest = ws + 524288 + 4194304;
    size_t rem = ws_size - 524288 - 4194304;

    // per-t footprint: cur only (512 KB)
    int Tc = (int)(rem / (size_t)(NB * 4));
    if (Tc > T_DIM) Tc = T_DIM;
    if (Tc < 1) Tc = 1;

    float* cur = (float*)rest;                               // Tc * 512 KB

    split_w_kernel<<<(N_DIM * I_DIM / 8) / 256, 256, 0, stream>>>(w, Wsp);

    int first = 1;
    for (int t0 = 0; t0 < T_DIM; ) {
        int tc = T_DIM - t0;
        if (tc > Tc) tc = Tc;

        spk_gemm_kernel<<<tc * 8, 256, 0, stream>>>((const uint8_t*)Wsp, x, cur, t0);
        spk_scan_kernel<<<NB / 256, 256, 0, stream>>>(cur, mp, out, tc, first);

        first = 0;
        t0 += tc;
    }
}